// Round 2
// baseline (8825.640 us; speedup 1.0000x reference)
//
#include <hip/hip_runtime.h>

namespace {

constexpr int NB    = 256;
constexpr int NT    = 1024;
constexpr int NSTEP = NT - 1;
constexpr int D = 4, H = 64, W = 128;

// RK coefficients (f32 casts of the reference doubles)
__device__ __constant__ float AT[6][5] = {
    {0.f, 0.f, 0.f, 0.f, 0.f},
    {0.161f, 0.f, 0.f, 0.f, 0.f},
    {-0.008480655492356989f, 0.335480655492357f, 0.f, 0.f, 0.f},
    {2.8971530571054935f, -6.359448489975075f, 4.3622954328695815f, 0.f, 0.f},
    {5.325864828439257f, -11.748883564062828f, 7.4955393428898365f, -0.09249506636175525f, 0.f},
    {5.86145544294642f, -12.92096931784711f, 8.159367898576159f, -0.071584973281401f, -0.028269050394068383f}};

__device__ __constant__ float FR[6] = {0.0f, 0.161f, 0.327f, 0.9f, 0.9800255409045097f, 1.0f};

__device__ __constant__ float BW[6] = {0.09646076681806523f, 0.01f, 0.4798896504144996f,
                                       1.379008574103742f, -3.290069515436081f, 2.324710524099774f};

__device__ __forceinline__ float softplus_f(float x) {
    float e = __expf(-fabsf(x));
    return fmaxf(x, 0.0f) + __logf(1.0f + e);
}

__device__ __forceinline__ float tanh_f(float x) {
    // tanh(x) = 1 - 2/(1+e^(2x)); stable for all x (inf handled by rcp -> 0)
    float e = __expf(2.0f * x);
    return 1.0f - __fdividef(2.0f, 1.0f + e);
}

__global__ __launch_bounds__(512, 2)
void cde_kernel(const float* __restrict__ ts,
                const float* __restrict__ coef_d,
                const float* __restrict__ coef_c,
                const float* __restrict__ coef_b,
                const float* __restrict__ coef_a,
                const float* __restrict__ W0, const float* __restrict__ b0,
                const float* __restrict__ W1, const float* __restrict__ b1,
                const float* __restrict__ W2, const float* __restrict__ b2,
                const float* __restrict__ F0, const float* __restrict__ g0,
                const float* __restrict__ F1, const float* __restrict__ g1,
                const float* __restrict__ F2, const float* __restrict__ g2,
                const float* __restrict__ Lm, const float* __restrict__ lb,
                float* __restrict__ out)
{
    const int b    = blockIdx.x;
    const int tid  = threadIdx.x;
    const int lane = tid & 63;

    const int j12 = tid >> 2;   // 0..127 : L1/L2 output index
    const int q12 = tid & 3;    //          h-slice within the dot
    const int j3  = tid >> 1;   // 0..255 : L3 output index
    const int q3  = tid & 1;
    const int d3  = j3 & 3;     // einsum d for this thread's f-element

    __shared__ __align__(16) float s_y[H];
    __shared__ __align__(16) float s_ys[H];
    __shared__ __align__(16) float s_h1[W];
    __shared__ __align__(16) float s_h2[W];
    __shared__ __align__(16) float s_k[6][H];

    // ---------------- persistent register-resident weights ----------------
    float wA[16];   // F0[j12][16*q12 .. +15]
    float wB[32];   // F1[j12][32*q12 .. +31]  (chunk-rotated by 2*q12 for bank spread)
    float wC[64];   // F2[j3 ][64*q3  .. +63]
    #pragma unroll
    for (int i = 0; i < 16; i += 4) {
        float4 v = *reinterpret_cast<const float4*>(F0 + j12 * H + q12 * 16 + i);
        wA[i+0]=v.x; wA[i+1]=v.y; wA[i+2]=v.z; wA[i+3]=v.w;
    }
    #pragma unroll
    for (int c = 0; c < 8; ++c) {
        const int lc = (c + 2 * q12) & 7;   // logical chunk held in register chunk c
        float4 v = *reinterpret_cast<const float4*>(F1 + j12 * W + q12 * 32 + lc * 4);
        wB[4*c+0]=v.x; wB[4*c+1]=v.y; wB[4*c+2]=v.z; wB[4*c+3]=v.w;
    }
    #pragma unroll
    for (int i = 0; i < 64; i += 4) {
        float4 v = *reinterpret_cast<const float4*>(F2 + j3 * W + q3 * 64 + i);
        wC[i+0]=v.x; wC[i+1]=v.y; wC[i+2]=v.z; wC[i+3]=v.w;
    }
    const float g0r = g0[j12];
    const float g1r = g1[j12];
    const float g2r = g2[j3];

    const float L0r = Lm[0*H + lane];
    const float L1r = Lm[1*H + lane];
    const float L2r = Lm[2*H + lane];
    const float lb0 = lb[0], lb1 = lb[1], lb2 = lb[2];

    // ---------------- initial y0 = MLP(x0) + out[b][0] ----------------
    if (tid < W) {
        const float4 x0 = *reinterpret_cast<const float4*>(coef_a + (size_t)b * NSTEP * D);
        const float4 w  = *reinterpret_cast<const float4*>(W0 + tid * D);
        s_h1[tid] = softplus_f(w.x*x0.x + w.y*x0.y + w.z*x0.z + w.w*x0.w + b0[tid]);
    }
    __syncthreads();
    if (tid < W) {
        float a = b1[tid];
        #pragma unroll 8
        for (int k = 0; k < W; k += 4) {
            float4 wv = *reinterpret_cast<const float4*>(W1 + tid * W + k);
            float4 hv = *reinterpret_cast<const float4*>(s_h1 + k);
            a += wv.x*hv.x + wv.y*hv.y + wv.z*hv.z + wv.w*hv.w;
        }
        s_h2[tid] = softplus_f(a);
    }
    __syncthreads();
    if (tid < H) {
        float a = b2[tid];
        #pragma unroll 8
        for (int k = 0; k < W; k += 4) {
            float4 wv = *reinterpret_cast<const float4*>(W2 + tid * W + k);
            float4 hv = *reinterpret_cast<const float4*>(s_h2 + k);
            a += wv.x*hv.x + wv.y*hv.y + wv.z*hv.z + wv.w*hv.w;
        }
        s_y[tid] = a;
        float p0 = a * L0r, p1 = a * L1r, p2 = a * L2r;
        #pragma unroll
        for (int off = 32; off >= 1; off >>= 1) {
            p0 += __shfl_xor(p0, off);
            p1 += __shfl_xor(p1, off);
            p2 += __shfl_xor(p2, off);
        }
        if (lane == 0) {
            float* dst = out + (size_t)b * NT * 3;
            dst[0] = p0 + lb0; dst[1] = p1 + lb1; dst[2] = p2 + lb2;
        }
    }
    __syncthreads();

    // ---------------- main scan: 1023 steps x 6 stages ----------------
    for (int t = 0; t < NSTEP; ++t) {
        // step-uniform data; issued early, consumed after >=1 layer of compute
        const size_t cofs = ((size_t)b * NSTEP + t) * D + d3;
        const float cbd = coef_b[cofs];
        const float ccd = coef_c[cofs];
        const float cdd = coef_d[cofs];
        const float dtv = ts[t + 1] - ts[t];

        #pragma unroll
        for (int s = 0; s < 6; ++s) {
            if (s > 0) {
                if (tid < H) {   // wave0 builds the stage state
                    float a = 0.0f;
                    #pragma unroll
                    for (int i = 0; i < s; ++i) a = fmaf(AT[s][i], s_k[i][tid], a);
                    s_ys[tid] = fmaf(dtv, a, s_y[tid]);
                }
                __syncthreads();
            }
            const float* act1 = (s == 0) ? s_y : s_ys;

            // ---- L1: 64 -> 128, 4 threads per output ----
            float a1 = 0.0f;
            #pragma unroll
            for (int i = 0; i < 16; i += 4) {
                float4 hv = *reinterpret_cast<const float4*>(act1 + q12 * 16 + i);
                a1 += wA[i]*hv.x + wA[i+1]*hv.y + wA[i+2]*hv.z + wA[i+3]*hv.w;
            }
            a1 += __shfl_xor(a1, 1);
            a1 += __shfl_xor(a1, 2);
            if (q12 == 0) s_h1[j12] = softplus_f(a1 + g0r);
            __syncthreads();

            // ---- L2: 128 -> 128, 4 threads per output (chunk-rotated) ----
            float a2 = 0.0f;
            #pragma unroll
            for (int c = 0; c < 8; ++c) {
                const int lc = (c + 2 * q12) & 7;
                float4 hv = *reinterpret_cast<const float4*>(s_h1 + q12 * 32 + lc * 4);
                a2 += wB[4*c]*hv.x + wB[4*c+1]*hv.y + wB[4*c+2]*hv.z + wB[4*c+3]*hv.w;
            }
            a2 += __shfl_xor(a2, 1);
            a2 += __shfl_xor(a2, 2);
            if (q12 == 0) s_h2[j12] = softplus_f(a2 + g1r);
            __syncthreads();

            // ---- L3: 128 -> 256, 2 threads per output, then einsum over d ----
            float a3 = 0.0f;
            #pragma unroll
            for (int i = 0; i < 64; i += 4) {
                float4 hv = *reinterpret_cast<const float4*>(s_h2 + q3 * 64 + i);
                a3 += wC[i]*hv.x + wC[i+1]*hv.y + wC[i+2]*hv.z + wC[i+3]*hv.w;
            }
            a3 += __shfl_xor(a3, 1);          // combine the two half-dots -> f[j3] in both lanes
            const float f = tanh_f(a3 + g2r);

            const float frac = FR[s] * dtv;
            const float dxd  = fmaf(frac, fmaf(3.0f * frac, cdd, 2.0f * ccd), cbd);
            // lanes {0,2,4,6} of each 8-lane group hold d=0..3 exactly once after
            // xor-2 / xor-4 (lane pairs 2j,2j+1 are duplicates) -> no 0.5 factor.
            float v = f * dxd;
            v += __shfl_xor(v, 2);
            v += __shfl_xor(v, 4);
            if ((tid & 7) == 0) s_k[s][tid >> 3] = v;
            __syncthreads();
        }

        // ---- y update + output projection (wave0) ----
        if (tid < H) {
            float a = 0.0f;
            #pragma unroll
            for (int i = 0; i < 6; ++i) a = fmaf(BW[i], s_k[i][tid], a);
            const float yn = fmaf(dtv, a, s_y[tid]);
            s_y[tid] = yn;
            float p0 = yn * L0r, p1 = yn * L1r, p2 = yn * L2r;
            #pragma unroll
            for (int off = 32; off >= 1; off >>= 1) {
                p0 += __shfl_xor(p0, off);
                p1 += __shfl_xor(p1, off);
                p2 += __shfl_xor(p2, off);
            }
            if (lane == 0) {
                float* dst = out + ((size_t)b * NT + (t + 1)) * 3;
                dst[0] = p0 + lb0; dst[1] = p1 + lb1; dst[2] = p2 + lb2;
            }
        }
        __syncthreads();
    }
}

} // namespace

extern "C" void kernel_launch(void* const* d_in, const int* in_sizes, int n_in,
                              void* d_out, int out_size, void* d_ws, size_t ws_size,
                              hipStream_t stream) {
    const float* ts     = (const float*)d_in[0];
    const float* coef_d = (const float*)d_in[1];
    const float* coef_c = (const float*)d_in[2];
    const float* coef_b = (const float*)d_in[3];
    const float* coef_a = (const float*)d_in[4];
    const float* W0 = (const float*)d_in[5];
    const float* b0 = (const float*)d_in[6];
    const float* W1 = (const float*)d_in[7];
    const float* b1 = (const float*)d_in[8];
    const float* W2 = (const float*)d_in[9];
    const float* b2 = (const float*)d_in[10];
    const float* F0 = (const float*)d_in[11];
    const float* g0 = (const float*)d_in[12];
    const float* F1 = (const float*)d_in[13];
    const float* g1 = (const float*)d_in[14];
    const float* F2 = (const float*)d_in[15];
    const float* g2 = (const float*)d_in[16];
    const float* Lm = (const float*)d_in[17];
    const float* lb = (const float*)d_in[18];
    float* out = (float*)d_out;

    hipLaunchKernelGGL(cde_kernel, dim3(NB), dim3(512), 0, stream,
                       ts, coef_d, coef_c, coef_b, coef_a,
                       W0, b0, W1, b1, W2, b2,
                       F0, g0, F1, g1, F2, g2, Lm, lb, out);
}

// Round 4
// 7795.992 us; speedup vs baseline: 1.1321x; 1.1321x over previous
//
#include <hip/hip_runtime.h>

namespace {

constexpr int NB    = 256;
constexpr int NT    = 1024;
constexpr int NSTEP = NT - 1;
constexpr int D = 4, H = 64, W = 128;

// RK coefficients (f32 casts of the reference doubles)
__device__ __constant__ float AT[6][5] = {
    {0.f, 0.f, 0.f, 0.f, 0.f},
    {0.161f, 0.f, 0.f, 0.f, 0.f},
    {-0.008480655492356989f, 0.335480655492357f, 0.f, 0.f, 0.f},
    {2.8971530571054935f, -6.359448489975075f, 4.3622954328695815f, 0.f, 0.f},
    {5.325864828439257f, -11.748883564062828f, 7.4955393428898365f, -0.09249506636175525f, 0.f},
    {5.86145544294642f, -12.92096931784711f, 8.159367898576159f, -0.071584973281401f, -0.028269050394068383f}};

__device__ __constant__ float FR[6] = {0.0f, 0.161f, 0.327f, 0.9f, 0.9800255409045097f, 1.0f};

__device__ __constant__ float BW[6] = {0.09646076681806523f, 0.01f, 0.4798896504144996f,
                                       1.379008574103742f, -3.290069515436081f, 2.324710524099774f};

// Pin a value into a VGPR: definition becomes opaque -> no rematerialization.
#define PIN(x) asm volatile("" : "+v"(x))

__device__ __forceinline__ float softplus_f(float x) {
    float e = __expf(-fabsf(x));
    return fmaxf(x, 0.0f) + __logf(1.0f + e);
}

__device__ __forceinline__ float tanh_f(float x) {
    float e = __expf(2.0f * x);
    return 1.0f - __fdividef(2.0f, 1.0f + e);
}

// DPP lane exchanges (VALU-speed, no DS pipe). All three are involutions,
// so the shr/ror direction ambiguity cannot bite.
__device__ __forceinline__ float dpp_xor1(float x) {   // quad_perm [1,0,3,2]
    return __int_as_float(__builtin_amdgcn_mov_dpp(__float_as_int(x), 0xB1, 0xF, 0xF, true));
}
__device__ __forceinline__ float dpp_xor2(float x) {   // quad_perm [2,3,0,1]
    return __int_as_float(__builtin_amdgcn_mov_dpp(__float_as_int(x), 0x4E, 0xF, 0xF, true));
}
__device__ __forceinline__ float dpp_half_mirror(float x) { // lane i <-> 7-i in each 8-lane half-row
    return __int_as_float(__builtin_amdgcn_mov_dpp(__float_as_int(x), 0x141, 0xF, 0xF, true));
}

__global__ __launch_bounds__(512, 2)
void cde_kernel(const float* __restrict__ ts,
                const float* __restrict__ coef_d,
                const float* __restrict__ coef_c,
                const float* __restrict__ coef_b,
                const float* __restrict__ coef_a,
                const float* __restrict__ W0, const float* __restrict__ b0,
                const float* __restrict__ W1, const float* __restrict__ b1,
                const float* __restrict__ W2, const float* __restrict__ b2,
                const float* __restrict__ F0, const float* __restrict__ g0,
                const float* __restrict__ F1, const float* __restrict__ g1,
                const float* __restrict__ F2, const float* __restrict__ g2,
                const float* __restrict__ Lm, const float* __restrict__ lb,
                float* __restrict__ out)
{
    const int b    = blockIdx.x;
    const int tid  = threadIdx.x;
    const int lane = tid & 63;

    const int j12 = tid >> 2;   // 0..127 : L1/L2 output index
    const int q12 = tid & 3;    //          h-slice within the dot
    const int j3  = tid >> 1;   // 0..255 : L3 output index
    const int q3  = tid & 1;
    const int d3  = j3 & 3;     // einsum d for this thread's f-element

    __shared__ __align__(16) float s_y[H];
    __shared__ __align__(16) float s_ys[H];
    __shared__ __align__(16) float s_h1[W];
    __shared__ __align__(16) float s_h2[W];
    __shared__ __align__(16) float s_k[6][H];

    // ---------------- persistent register-resident weights ----------------
    float wA[16];   // F0[j12][16*q12 .. +15]
    float wB[32];   // F1[j12][32*q12 .. +31]  (chunk-rotated by 2*q12)
    float wC[64];   // F2[j3 ][64*q3  .. +63]
    #pragma unroll
    for (int i = 0; i < 16; i += 4) {
        float4 v = *reinterpret_cast<const float4*>(F0 + j12 * H + q12 * 16 + i);
        wA[i+0]=v.x; wA[i+1]=v.y; wA[i+2]=v.z; wA[i+3]=v.w;
    }
    #pragma unroll
    for (int c = 0; c < 8; ++c) {
        const int lc = (c + 2 * q12) & 7;
        float4 v = *reinterpret_cast<const float4*>(F1 + j12 * W + q12 * 32 + lc * 4);
        wB[4*c+0]=v.x; wB[4*c+1]=v.y; wB[4*c+2]=v.z; wB[4*c+3]=v.w;
    }
    #pragma unroll
    for (int i = 0; i < 64; i += 4) {
        float4 v = *reinterpret_cast<const float4*>(F2 + j3 * W + q3 * 64 + i);
        wC[i+0]=v.x; wC[i+1]=v.y; wC[i+2]=v.z; wC[i+3]=v.w;
    }
    float g0r = g0[j12];
    float g1r = g1[j12];
    float g2r = g2[j3];
    float L0r = Lm[0*H + lane];
    float L1r = Lm[1*H + lane];
    float L2r = Lm[2*H + lane];
    const float lb0 = lb[0], lb1 = lb[1], lb2 = lb[2];

    // Force register residency across the whole scan.
    #pragma unroll
    for (int i = 0; i < 16; ++i) PIN(wA[i]);
    #pragma unroll
    for (int i = 0; i < 32; ++i) PIN(wB[i]);
    #pragma unroll
    for (int i = 0; i < 64; ++i) PIN(wC[i]);
    PIN(g0r); PIN(g1r); PIN(g2r); PIN(L0r); PIN(L1r); PIN(L2r);

    // ---------------- initial y0 = MLP(x0) + out[b][0] ----------------
    if (tid < W) {
        const float4 x0 = *reinterpret_cast<const float4*>(coef_a + (size_t)b * NSTEP * D);
        const float4 w  = *reinterpret_cast<const float4*>(W0 + tid * D);
        s_h1[tid] = softplus_f(w.x*x0.x + w.y*x0.y + w.z*x0.z + w.w*x0.w + b0[tid]);
    }
    __syncthreads();
    if (tid < W) {
        float a = b1[tid];
        #pragma unroll 8
        for (int k = 0; k < W; k += 4) {
            float4 wv = *reinterpret_cast<const float4*>(W1 + tid * W + k);
            float4 hv = *reinterpret_cast<const float4*>(s_h1 + k);
            a += wv.x*hv.x + wv.y*hv.y + wv.z*hv.z + wv.w*hv.w;
        }
        s_h2[tid] = softplus_f(a);
    }
    __syncthreads();
    if (tid < H) {
        float a = b2[tid];
        #pragma unroll 8
        for (int k = 0; k < W; k += 4) {
            float4 wv = *reinterpret_cast<const float4*>(W2 + tid * W + k);
            float4 hv = *reinterpret_cast<const float4*>(s_h2 + k);
            a += wv.x*hv.x + wv.y*hv.y + wv.z*hv.z + wv.w*hv.w;
        }
        s_y[tid] = a;
        float p0 = a * L0r, p1 = a * L1r, p2 = a * L2r;
        #pragma unroll
        for (int off = 32; off >= 1; off >>= 1) {
            p0 += __shfl_xor(p0, off);
            p1 += __shfl_xor(p1, off);
            p2 += __shfl_xor(p2, off);
        }
        if (lane == 0) {
            float* dst = out + (size_t)b * NT * 3;
            dst[0] = p0 + lb0; dst[1] = p1 + lb1; dst[2] = p2 + lb2;
        }
    }
    __syncthreads();

    // ---------------- main scan: 1023 steps x 6 stages ----------------
    for (int t = 0; t < NSTEP; ++t) {
        const size_t cofs = ((size_t)b * NSTEP + t) * D + d3;
        const float cbd = coef_b[cofs];
        const float ccd = coef_c[cofs];
        const float cdd = coef_d[cofs];
        const float dtv = ts[t + 1] - ts[t];

        #pragma unroll
        for (int s = 0; s < 6; ++s) {
            if (s > 0) {
                if (tid < H) {   // wave0 builds the stage state
                    float a = 0.0f;
                    #pragma unroll
                    for (int i = 0; i < s; ++i) a = fmaf(AT[s][i], s_k[i][tid], a);
                    s_ys[tid] = fmaf(dtv, a, s_y[tid]);
                }
                __syncthreads();
            }
            const float* act1 = (s == 0) ? s_y : s_ys;

            // ---- L1: 64 -> 128, 4 threads per output ----
            float a1 = 0.0f;
            #pragma unroll
            for (int i = 0; i < 16; i += 4) {
                float4 hv = *reinterpret_cast<const float4*>(act1 + q12 * 16 + i);
                a1 += wA[i]*hv.x + wA[i+1]*hv.y + wA[i+2]*hv.z + wA[i+3]*hv.w;
            }
            a1 += dpp_xor1(a1);
            a1 += dpp_xor2(a1);
            if (q12 == 0) s_h1[j12] = softplus_f(a1 + g0r);
            __syncthreads();

            // ---- L2: 128 -> 128, 4 threads per output (chunk-rotated) ----
            float a2a = 0.0f, a2b = 0.0f;
            #pragma unroll
            for (int c = 0; c < 8; c += 2) {
                const int lc0 = (c + 2 * q12) & 7;
                const int lc1 = (c + 1 + 2 * q12) & 7;
                float4 h0 = *reinterpret_cast<const float4*>(s_h1 + q12 * 32 + lc0 * 4);
                float4 h1 = *reinterpret_cast<const float4*>(s_h1 + q12 * 32 + lc1 * 4);
                a2a += wB[4*c+0]*h0.x + wB[4*c+1]*h0.y + wB[4*c+2]*h0.z + wB[4*c+3]*h0.w;
                a2b += wB[4*c+4]*h1.x + wB[4*c+5]*h1.y + wB[4*c+6]*h1.z + wB[4*c+7]*h1.w;
            }
            float a2 = a2a + a2b;
            a2 += dpp_xor1(a2);
            a2 += dpp_xor2(a2);
            if (q12 == 0) s_h2[j12] = softplus_f(a2 + g1r);
            __syncthreads();

            // ---- L3: 128 -> 256, 2 threads per output, then einsum over d ----
            float a3a = 0.0f, a3b = 0.0f;
            #pragma unroll
            for (int i = 0; i < 64; i += 8) {
                float4 h0 = *reinterpret_cast<const float4*>(s_h2 + q3 * 64 + i);
                float4 h1 = *reinterpret_cast<const float4*>(s_h2 + q3 * 64 + i + 4);
                a3a += wC[i+0]*h0.x + wC[i+1]*h0.y + wC[i+2]*h0.z + wC[i+3]*h0.w;
                a3b += wC[i+4]*h1.x + wC[i+5]*h1.y + wC[i+6]*h1.z + wC[i+7]*h1.w;
            }
            float a3 = a3a + a3b;
            a3 += dpp_xor1(a3);               // combine the two half-dots -> f[j3]
            const float f = tanh_f(a3 + g2r);

            const float frac = FR[s] * dtv;
            const float dxd  = fmaf(frac, fmaf(3.0f * frac, cdd, 2.0f * ccd), cbd);
            // After xor2, lanes 0-3 of each 8-group hold d0+d1 and lanes 4-7
            // hold d2+d3; half_mirror (involution) pairs lane i with 7-i,
            // completing the d-sum on every lane of the group.
            float v = f * dxd;
            v += dpp_xor2(v);
            v += dpp_half_mirror(v);
            if ((tid & 7) == 0) s_k[s][tid >> 3] = v;
            __syncthreads();
        }

        // ---- y update + output projection (wave0) ----
        if (tid < H) {
            float a = 0.0f;
            #pragma unroll
            for (int i = 0; i < 6; ++i) a = fmaf(BW[i], s_k[i][tid], a);
            const float yn = fmaf(dtv, a, s_y[tid]);
            s_y[tid] = yn;
            float p0 = yn * L0r, p1 = yn * L1r, p2 = yn * L2r;
            #pragma unroll
            for (int off = 32; off >= 1; off >>= 1) {
                p0 += __shfl_xor(p0, off);
                p1 += __shfl_xor(p1, off);
                p2 += __shfl_xor(p2, off);
            }
            if (lane == 0) {
                float* dst = out + ((size_t)b * NT + (t + 1)) * 3;
                dst[0] = p0 + lb0; dst[1] = p1 + lb1; dst[2] = p2 + lb2;
            }
        }
        __syncthreads();
    }
}

} // namespace

extern "C" void kernel_launch(void* const* d_in, const int* in_sizes, int n_in,
                              void* d_out, int out_size, void* d_ws, size_t ws_size,
                              hipStream_t stream) {
    const float* ts     = (const float*)d_in[0];
    const float* coef_d = (const float*)d_in[1];
    const float* coef_c = (const float*)d_in[2];
    const float* coef_b = (const float*)d_in[3];
    const float* coef_a = (const float*)d_in[4];
    const float* W0 = (const float*)d_in[5];
    const float* b0 = (const float*)d_in[6];
    const float* W1 = (const float*)d_in[7];
    const float* b1 = (const float*)d_in[8];
    const float* W2 = (const float*)d_in[9];
    const float* b2 = (const float*)d_in[10];
    const float* F0 = (const float*)d_in[11];
    const float* g0 = (const float*)d_in[12];
    const float* F1 = (const float*)d_in[13];
    const float* g1 = (const float*)d_in[14];
    const float* F2 = (const float*)d_in[15];
    const float* g2 = (const float*)d_in[16];
    const float* Lm = (const float*)d_in[17];
    const float* lb = (const float*)d_in[18];
    float* out = (float*)d_out;

    hipLaunchKernelGGL(cde_kernel, dim3(NB), dim3(512), 0, stream,
                       ts, coef_d, coef_c, coef_b, coef_a,
                       W0, b0, W1, b1, W2, b2,
                       F0, g0, F1, g1, F2, g2, Lm, lb, out);
}

// Round 6
// 6908.459 us; speedup vs baseline: 1.2775x; 1.1285x over previous
//
#include <hip/hip_runtime.h>

namespace {

constexpr int NB    = 256;
constexpr int NT    = 1024;
constexpr int NSTEP = NT - 1;
constexpr int D = 4, H = 64, W = 128;

// RK coefficients as compile-time constants (fold to immediates).
constexpr float cAT[6][5] = {
    {0.f, 0.f, 0.f, 0.f, 0.f},
    {0.161f, 0.f, 0.f, 0.f, 0.f},
    {-0.008480655492356989f, 0.335480655492357f, 0.f, 0.f, 0.f},
    {2.8971530571054935f, -6.359448489975075f, 4.3622954328695815f, 0.f, 0.f},
    {5.325864828439257f, -11.748883564062828f, 7.4955393428898365f, -0.09249506636175525f, 0.f},
    {5.86145544294642f, -12.92096931784711f, 8.159367898576159f, -0.071584973281401f, -0.028269050394068383f}};
constexpr float cFR[6] = {0.0f, 0.161f, 0.327f, 0.9f, 0.9800255409045097f, 1.0f};
constexpr float cBW[6] = {0.09646076681806523f, 0.01f, 0.4798896504144996f,
                          1.379008574103742f, -3.290069515436081f, 2.324710524099774f};

__device__ __forceinline__ float softplus_f(float x) {
    float e = __expf(-fabsf(x));
    return fmaxf(x, 0.0f) + __logf(1.0f + e);
}
__device__ __forceinline__ float tanh_f(float x) {
    float e = __expf(2.0f * x);
    return 1.0f - __fdividef(2.0f, 1.0f + e);
}

// DPP lane exchange (VALU pipe, no DS). Only HW-validated patterns (round 4):
// 0xB1 quad_perm[1,0,3,2] (xor1) | 0x4E quad_perm[2,3,0,1] (xor2)
// 0x141 row_half_mirror (i<->7-i within each 8-lane half-row)
template <int CTRL>
__device__ __forceinline__ float dppmv(float x) {
    return __int_as_float(__builtin_amdgcn_mov_dpp(__float_as_int(x), CTRL, 0xF, 0xF, true));
}

// Padded LDS index maps (conflict-free broadcast reads, 16B-aligned float4):
__device__ __forceinline__ int pY(int i)  { return (i >> 4) * 20 + (i & 15); }  // s_ys : 4x20
__device__ __forceinline__ int p1i(int i) { return (i >> 5) * 36 + (i & 31); }  // s_h1 : 4x36
__device__ __forceinline__ int p2i(int i) { return (i >> 6) * 72 + (i & 63); }  // s_h2 : 2x72

__global__ __launch_bounds__(512, 2)
void cde_kernel(const float* __restrict__ ts,
                const float* __restrict__ coef_d,
                const float* __restrict__ coef_c,
                const float* __restrict__ coef_b,
                const float* __restrict__ coef_a,
                const float* __restrict__ W0, const float* __restrict__ b0,
                const float* __restrict__ W1, const float* __restrict__ b1,
                const float* __restrict__ W2, const float* __restrict__ b2,
                const float* __restrict__ F0, const float* __restrict__ g0,
                const float* __restrict__ F1, const float* __restrict__ g1,
                const float* __restrict__ F2, const float* __restrict__ g2,
                const float* __restrict__ Lm, const float* __restrict__ lb,
                float* __restrict__ out)
{
    const int b    = blockIdx.x;
    const int tid  = threadIdx.x;

    const int j12  = tid >> 2;   // 0..127 : L1/L2 output index
    const int q12  = tid & 3;    //          k-slice within the dot
    const int j3   = tid >> 1;   // 0..255 : L3 output index
    const int q3   = tid & 1;
    const int d3   = j3 & 3;     // einsum d for this thread's f-element
    const int hown = tid >> 3;   // the y/k element this 8-lane group owns

    __shared__ __align__(16) float s_ys[80];    // stage state (padded 4x20)
    __shared__ __align__(16) float s_h1[144];   // layer-1 act  (padded 4x36)
    __shared__ __align__(16) float s_h2[136];   // layer-2 act  (padded 2x72)

    // ---------------- persistent register-resident weights ----------------
    float wA[16];   // F0[j12][16*q12 .. +15]
    float wB[32];   // F1[j12][32*q12 .. +31]
    float wC[64];   // F2[j3 ][64*q3  .. +63]
    #pragma unroll
    for (int i = 0; i < 16; i += 4) {
        float4 v = *reinterpret_cast<const float4*>(F0 + j12 * H + q12 * 16 + i);
        wA[i+0]=v.x; wA[i+1]=v.y; wA[i+2]=v.z; wA[i+3]=v.w;
    }
    #pragma unroll
    for (int i = 0; i < 32; i += 4) {
        float4 v = *reinterpret_cast<const float4*>(F1 + j12 * W + q12 * 32 + i);
        wB[i+0]=v.x; wB[i+1]=v.y; wB[i+2]=v.z; wB[i+3]=v.w;
    }
    #pragma unroll
    for (int i = 0; i < 64; i += 4) {
        float4 v = *reinterpret_cast<const float4*>(F2 + j3 * W + q3 * 64 + i);
        wC[i+0]=v.x; wC[i+1]=v.y; wC[i+2]=v.z; wC[i+3]=v.w;
    }
    const float g0r = g0[j12];
    const float g1r = g1[j12];
    const float g2r = g2[j3];
    const float L0r = Lm[0*H + (tid & 63)];
    const float L1r = Lm[1*H + (tid & 63)];
    const float L2r = Lm[2*H + (tid & 63)];
    const float lb0 = lb[0], lb1 = lb[1], lb2 = lb[2];

    // Precomputed LDS base pointers (all broadcast-read bases 16B-aligned).
    const float* pA  = s_ys + q12 * 20;      // L1 act: float4 at +0,+4,+8,+12
    const float* pB  = s_h1 + q12 * 36;      // L2 act: float4 at +4c, c=0..7
    const float* pC  = s_h2 + q3  * 72;      // L3 act: float4 at +4c, c=0..15
    float* pw1 = s_h1 + p1i(j12);
    float* pw2 = s_h2 + p2i(j12);
    float* pwy = s_ys + pY(hown);

    // ---------------- initial y0 = MLP(x0) ----------------
    if (tid < W) {
        const float4 x0 = *reinterpret_cast<const float4*>(coef_a + (size_t)b * NSTEP * D);
        const float4 w  = *reinterpret_cast<const float4*>(W0 + tid * D);
        s_h1[p1i(tid)] = softplus_f(w.x*x0.x + w.y*x0.y + w.z*x0.z + w.w*x0.w + b0[tid]);
    }
    __syncthreads();
    if (tid < W) {
        float a = b1[tid];
        #pragma unroll
        for (int blk = 0; blk < 4; ++blk)
            #pragma unroll
            for (int i = 0; i < 8; ++i) {
                float4 wv = *reinterpret_cast<const float4*>(W1 + tid * W + blk * 32 + 4 * i);
                float4 hv = *reinterpret_cast<const float4*>(s_h1 + blk * 36 + 4 * i);
                a += wv.x*hv.x + wv.y*hv.y + wv.z*hv.z + wv.w*hv.w;
            }
        s_h2[p2i(tid)] = softplus_f(a);
    }
    __syncthreads();
    if (tid < H) {
        float a = b2[tid];
        #pragma unroll
        for (int blk = 0; blk < 2; ++blk)
            #pragma unroll
            for (int i = 0; i < 16; ++i) {
                float4 wv = *reinterpret_cast<const float4*>(W2 + tid * W + blk * 64 + 4 * i);
                float4 hv = *reinterpret_cast<const float4*>(s_h2 + blk * 72 + 4 * i);
                a += wv.x*hv.x + wv.y*hv.y + wv.z*hv.z + wv.w*hv.w;
            }
        s_ys[pY(tid)] = a;
    }
    __syncthreads();

    // Every lane's registered copy of its group's y element.
    float y = s_ys[pY(hown)];

    // Output projection: round-4-validated 64-lane shfl_xor butterfly (wave0).
    auto project = [&](int tslot) {
        if (tid < 64) {
            float yv = s_ys[pY(tid)];
            float p0 = yv * L0r, p1 = yv * L1r, p2 = yv * L2r;
            #pragma unroll
            for (int off = 32; off >= 1; off >>= 1) {
                p0 += __shfl_xor(p0, off);
                p1 += __shfl_xor(p1, off);
                p2 += __shfl_xor(p2, off);
            }
            if (tid == 0) {
                float* dst = out + ((size_t)b * NT + tslot) * 3;
                dst[0] = p0 + lb0; dst[1] = p1 + lb1; dst[2] = p2 + lb2;
            }
        }
    };
    project(0);

    const float* cb_p = coef_b + (size_t)b * NSTEP * D + d3;
    const float* cc_p = coef_c + (size_t)b * NSTEP * D + d3;
    const float* cd_p = coef_d + (size_t)b * NSTEP * D + d3;

    // ---------------- main scan: 1023 steps x 6 stages, 3 barriers/stage ----------------
    for (int t = 0; t < NSTEP; ++t) {
        const float cbd = cb_p[t * D];
        const float ccd = cc_p[t * D];
        const float cdd = cd_p[t * D];
        const float dtv = ts[t + 1] - ts[t];

        float k[6];

        #pragma unroll
        for (int s = 0; s < 6; ++s) {
            // ---- Phase A: L1 (64 -> 128), act = s_ys ----
            float4 h0 = *reinterpret_cast<const float4*>(pA + 0);
            float4 h1 = *reinterpret_cast<const float4*>(pA + 4);
            float4 h2 = *reinterpret_cast<const float4*>(pA + 8);
            float4 h3 = *reinterpret_cast<const float4*>(pA + 12);
            float a1  = wA[0]*h0.x + wA[1]*h0.y + wA[2]*h0.z + wA[3]*h0.w
                      + wA[4]*h1.x + wA[5]*h1.y + wA[6]*h1.z + wA[7]*h1.w;
            float a1b = wA[8]*h2.x + wA[9]*h2.y + wA[10]*h2.z + wA[11]*h2.w
                      + wA[12]*h3.x + wA[13]*h3.y + wA[14]*h3.z + wA[15]*h3.w;
            float a1s = a1 + a1b;
            a1s += dppmv<0xB1>(a1s);
            a1s += dppmv<0x4E>(a1s);
            if (q12 == 0) *pw1 = softplus_f(a1s + g0r);
            __syncthreads();

            // ---- Phase B: L2 (128 -> 128) ----
            float a2 = 0.f, a2b = 0.f;
            #pragma unroll
            for (int c = 0; c < 8; c += 2) {
                float4 u0 = *reinterpret_cast<const float4*>(pB + 4 * c);
                float4 u1 = *reinterpret_cast<const float4*>(pB + 4 * c + 4);
                a2  += wB[4*c+0]*u0.x + wB[4*c+1]*u0.y + wB[4*c+2]*u0.z + wB[4*c+3]*u0.w;
                a2b += wB[4*c+4]*u1.x + wB[4*c+5]*u1.y + wB[4*c+6]*u1.z + wB[4*c+7]*u1.w;
            }
            float a2s = a2 + a2b;
            a2s += dppmv<0xB1>(a2s);
            a2s += dppmv<0x4E>(a2s);
            if (q12 == 0) *pw2 = softplus_f(a2s + g1r);
            __syncthreads();

            // ---- Phase C: L3 (128 -> 256) + einsum + in-register RK update ----
            float a3 = 0.f, a3b = 0.f;
            #pragma unroll
            for (int c = 0; c < 16; c += 2) {
                float4 u0 = *reinterpret_cast<const float4*>(pC + 4 * c);
                float4 u1 = *reinterpret_cast<const float4*>(pC + 4 * c + 4);
                a3  += wC[4*c+0]*u0.x + wC[4*c+1]*u0.y + wC[4*c+2]*u0.z + wC[4*c+3]*u0.w;
                a3b += wC[4*c+4]*u1.x + wC[4*c+5]*u1.y + wC[4*c+6]*u1.z + wC[4*c+7]*u1.w;
            }
            float a3s = a3 + a3b;
            a3s += dppmv<0xB1>(a3s);              // pair-combine -> f[j3] on both lanes
            const float f = tanh_f(a3s + g2r);

            const float frac = cFR[s] * dtv;
            const float dxd  = fmaf(frac, fmaf(3.0f * frac, cdd, 2.0f * ccd), cbd);
            // lanes 0-3 of 8-group: d0+d1 after xor2; 4-7: d2+d3; half-mirror completes.
            float v = f * dxd;
            v += dppmv<0x4E>(v);
            v += dppmv<0x141>(v);
            k[s] = v;                              // k_s[hown] (exact on writer lane)

            float ysn;
            if (s < 5) {
                float acc = 0.f;
                #pragma unroll
                for (int i = 0; i <= s; ++i) acc = fmaf(cAT[s+1][i], k[i], acc);
                ysn = fmaf(dtv, acc, y);
            } else {
                float acc = 0.f;
                #pragma unroll
                for (int i = 0; i < 6; ++i) acc = fmaf(cBW[i], k[i], acc);
                ysn = fmaf(dtv, acc, y);           // y_{t+1}
            }
            if ((tid & 7) == 0) *pwy = ysn;
            __syncthreads();
        }

        // Re-sync per-lane y from the single source of truth (writer lane's value):
        // correctness now depends only on the writer lane, as in round 4.
        y = s_ys[pY(hown)];

        // wave0 projects while the other waves run the next step's phase A.
        project(t + 1);
    }
}

} // namespace

extern "C" void kernel_launch(void* const* d_in, const int* in_sizes, int n_in,
                              void* d_out, int out_size, void* d_ws, size_t ws_size,
                              hipStream_t stream) {
    const float* ts     = (const float*)d_in[0];
    const float* coef_d = (const float*)d_in[1];
    const float* coef_c = (const float*)d_in[2];
    const float* coef_b = (const float*)d_in[3];
    const float* coef_a = (const float*)d_in[4];
    const float* W0 = (const float*)d_in[5];
    const float* b0 = (const float*)d_in[6];
    const float* W1 = (const float*)d_in[7];
    const float* b1 = (const float*)d_in[8];
    const float* W2 = (const float*)d_in[9];
    const float* b2 = (const float*)d_in[10];
    const float* F0 = (const float*)d_in[11];
    const float* g0 = (const float*)d_in[12];
    const float* F1 = (const float*)d_in[13];
    const float* g1 = (const float*)d_in[14];
    const float* F2 = (const float*)d_in[15];
    const float* g2 = (const float*)d_in[16];
    const float* Lm = (const float*)d_in[17];
    const float* lb = (const float*)d_in[18];
    float* out = (float*)d_out;

    hipLaunchKernelGGL(cde_kernel, dim3(NB), dim3(512), 0, stream,
                       ts, coef_d, coef_c, coef_b, coef_a,
                       W0, b0, W1, b1, W2, b2,
                       F0, g0, F1, g1, F2, g2, Lm, lb, out);
}